// Round 8
// baseline (294.931 us; speedup 1.0000x reference)
//
#include <hip/hip_runtime.h>
#include <hip/hip_bf16.h>
#include <math.h>

// Problem constants (fixed by reference setup_inputs)
#define BB 16
#define NN 64
#define ATTR 4
#define STATE 16
#define RELD 9
#define GG 32
#define NF 256
#define NROWS_OBJ (BB*NN)        // 1024
#define NROWS_REL (BB*NN*NN)     // 65536

typedef __bf16 bf16x8 __attribute__((ext_vector_type(8)));
typedef float  floatx4 __attribute__((ext_vector_type(4)));
typedef unsigned short ushort_t;

__device__ __forceinline__ ushort_t f2bf(float f) {
  unsigned int u = __float_as_uint(f);
  unsigned int r = (u + 0x7fffu + ((u >> 16) & 1u)) >> 16;
  return (ushort_t)r;
}
__device__ __forceinline__ float bf2f(ushort_t u) {
  return __uint_as_float(((unsigned int)u) << 16);
}
// bf16x3 split: x ~= h + l with |x-(h+l)| ~ 2^-18 |x|
__device__ __forceinline__ void split2(float x, ushort_t& h, ushort_t& l) {
  h = f2bf(x);
  float r = x - bf2f(h);
  l = f2bf(r);
}

#define F0_ELEMS (2 * 16 * 64 * 8)   // 16384
#define F1_ELEMS (8 * 16 * 64 * 8)   // 65536
#define F_TOTAL  (F0_ELEMS + 2 * F1_ELEMS)

// ---------------------------------------------------------------------------
// Fused encoder + Q/R + weight-fragment prep. 1024 threads (16 waves/CU):
// rows parallel across waves: thread (r = t>>8, c = t&255).
// ---------------------------------------------------------------------------
__global__ __launch_bounds__(1024) void enc_qr_prep_kernel(
    const float* __restrict__ attrs, const float* __restrict__ states,
    const float* __restrict__ w0, const float* __restrict__ b0,
    const float* __restrict__ w1, const float* __restrict__ b1,
    const float* __restrict__ rpw, const float* __restrict__ rpb,
    const float* __restrict__ rel_w0, const float* __restrict__ rel_w1,
    ushort_t* __restrict__ F0h, ushort_t* __restrict__ F0l,
    ushort_t* __restrict__ F1h, ushort_t* __restrict__ F1l,
    ushort_t* __restrict__ F2h, ushort_t* __restrict__ F2l,
    float* __restrict__ obj, float* __restrict__ Q, float* __restrict__ R)
{
  int tid = threadIdx.x;
  // ---- weight-fragment prep (single grid-stride pass: 256*1024 >= F_TOTAL)
  for (int idx = blockIdx.x * 1024 + tid; idx < F_TOTAL; idx += 256 * 1024) {
    if (idx < F0_ELEMS) {
      int j = idx & 7, lane = (idx >> 3) & 63, g = (idx >> 9) & 15, s = idx >> 13;
      int k = s * 32 + (lane >> 4) * 8 + j, n = g * 16 + (lane & 15);
      float v = (k < 33) ? rel_w0[k * NF + n] : 0.f;
      split2(v, F0h[idx], F0l[idx]);
    } else if (idx < F0_ELEMS + F1_ELEMS) {
      int t = idx - F0_ELEMS;
      int j = t & 7, lane = (t >> 3) & 63, g = (t >> 9) & 15, s = t >> 13;
      int k = s * 32 + (lane >> 4) * 8 + j, n = g * 16 + (lane & 15);
      split2(rel_w1[k * NF + n], F1h[t], F1l[t]);
    } else {
      int t = idx - (F0_ELEMS + F1_ELEMS);
      int j = t & 7, lane = (t >> 3) & 63, g = (t >> 9) & 15, s = t >> 13;
      int k = s * 32 + (lane >> 4) * 8 + j, n = g * 16 + (lane & 15);
      split2(rpw[k * NF + n], F2h[t], F2l[t]);
    }
  }
  // ---- encoder + Q/R, 4 rows/block, thread = (row, col)
  __shared__ float X[4 * 20];
  __shared__ float H[4 * NF];
  __shared__ float O[4 * NF];
  int row0 = blockIdx.x * 4;
  if (tid < 80) {
    int r = tid / 20, k = tid % 20;
    int m = row0 + r;
    X[tid] = (k < ATTR) ? attrs[m * ATTR + k] : states[m * STATE + (k - ATTR)];
  }
  __syncthreads();
  int r = tid >> 8, c = tid & 255;
  float a = b0[c];
#pragma unroll
  for (int k = 0; k < 20; ++k) a += X[r * 20 + k] * w0[k * NF + c];
  H[r * NF + c] = fmaxf(a, 0.f);
  __syncthreads();
  a = b1[c];
#pragma unroll 8
  for (int k = 0; k < NF; ++k) a += H[r * NF + k] * w1[k * NF + c];
  a = fmaxf(a, 0.f);
  O[r * NF + c] = a;
  obj[(row0 + r) * NF + c] = a;
  __syncthreads();
  a = rpb[c];
#pragma unroll 8
  for (int k = 0; k < NF; ++k) a += O[r * NF + k] * rpw[(256 + k) * NF + c];
  Q[(row0 + r) * NF + c] = a;
  a = 0.f;
#pragma unroll 8
  for (int k = 0; k < NF; ++k) a += O[r * NF + k] * rpw[(512 + k) * NF + c];
  R[(row0 + r) * NF + c] = a;
}

// ---------------------------------------------------------------------------
// Relation chain, bf16x3 split MFMA, software-pipelined (UNCHANGED from R5:
// ~70 us proven; ROWS=32, X aliased onto H, 33.8KB LDS -> 4 blocks/CU).
// ---------------------------------------------------------------------------
#define ROWS 32
#define NRT 2
#define HSTR 264
#define XSTR 72

__global__ __launch_bounds__(256, 4) void rel_chain_mfma(
    const float* __restrict__ attrs, const float* __restrict__ states,
    const float* __restrict__ rel_attrs,
    const ushort_t* __restrict__ F0h, const ushort_t* __restrict__ F0l,
    const float* __restrict__ b0,
    const ushort_t* __restrict__ F1h, const ushort_t* __restrict__ F1l,
    const float* __restrict__ b1,
    const ushort_t* __restrict__ F2h, const ushort_t* __restrict__ F2l,
    float* __restrict__ P)
{
  __shared__ __align__(16) ushort_t Hh[ROWS * HSTR];
  __shared__ __align__(16) ushort_t Hl[ROWS * HSTR];
  ushort_t* Xh = Hh;
  ushort_t* Xl = Hl;

  int tid  = threadIdx.x;
  int wave = tid >> 6;
  int lane = tid & 63;
  int quad = lane >> 4;
  int l16  = lane & 15;
  int row0 = blockIdx.x * ROWS;

  for (int idx = tid; idx < ROWS * 64; idx += 256) {
    int r = idx >> 6, k = idx & 63;
    int grow = row0 + r;
    int j = grow & 63, i = (grow >> 6) & 63, b = grow >> 12;
    float v = 0.f;
    if (k < RELD)                     v = rel_attrs[(size_t)grow * RELD + k];
    else if (k < RELD + STATE)        v = states[(b * NN + i) * STATE + (k - RELD)]
                                        - states[(b * NN + j) * STATE + (k - RELD)];
    else if (k < RELD + STATE + ATTR) v = attrs[(b * NN + i) * ATTR + (k - RELD - STATE)];
    else if (k < 33)                  v = attrs[(b * NN + j) * ATTR + (k - RELD - STATE - ATTR)];
    ushort_t h, l; split2(v, h, l);
    Xh[r * XSTR + k] = h;
    Xl[r * XSTR + k] = l;
  }
  __syncthreads();

  floatx4 acc[NRT][4];

#define ZERO_ACC() do { \
  _Pragma("unroll") for (int rt = 0; rt < NRT; ++rt) \
  _Pragma("unroll") for (int ct = 0; ct < 4; ++ct) acc[rt][ct] = (floatx4)(0.f); } while (0)

#define STAGE(S, AH, AL, ASTR, BH, BL) do { \
  bf16x8 ah[2][NRT], al[2][NRT], bh[2][4], bl[2][4]; \
  _Pragma("unroll") for (int ct = 0; ct < 4; ++ct) { \
    bh[0][ct] = *(const bf16x8*)((BH) + (size_t)((wave * 4 + ct) * 64 + lane) * 8); \
    bl[0][ct] = *(const bf16x8*)((BL) + (size_t)((wave * 4 + ct) * 64 + lane) * 8); } \
  _Pragma("unroll") for (int rt = 0; rt < NRT; ++rt) { \
    ah[0][rt] = *(const bf16x8*)(&(AH)[(rt * 16 + l16) * (ASTR) + quad * 8]); \
    al[0][rt] = *(const bf16x8*)(&(AL)[(rt * 16 + l16) * (ASTR) + quad * 8]); } \
  _Pragma("unroll") \
  for (int s = 0; s < (S); ++s) { \
    int cur = s & 1, nxt = cur ^ 1; \
    if (s + 1 < (S)) { \
      _Pragma("unroll") for (int ct = 0; ct < 4; ++ct) { \
        bh[nxt][ct] = *(const bf16x8*)((BH) + (size_t)(((s + 1) * 16 + wave * 4 + ct) * 64 + lane) * 8); \
        bl[nxt][ct] = *(const bf16x8*)((BL) + (size_t)(((s + 1) * 16 + wave * 4 + ct) * 64 + lane) * 8); } \
      _Pragma("unroll") for (int rt = 0; rt < NRT; ++rt) { \
        ah[nxt][rt] = *(const bf16x8*)(&(AH)[(rt * 16 + l16) * (ASTR) + (s + 1) * 32 + quad * 8]); \
        al[nxt][rt] = *(const bf16x8*)(&(AL)[(rt * 16 + l16) * (ASTR) + (s + 1) * 32 + quad * 8]); } } \
    _Pragma("unroll") for (int rt = 0; rt < NRT; ++rt) \
    _Pragma("unroll") for (int ct = 0; ct < 4; ++ct) { \
      acc[rt][ct] = __builtin_amdgcn_mfma_f32_16x16x32_bf16(ah[cur][rt], bh[cur][ct], acc[rt][ct], 0, 0, 0); \
      acc[rt][ct] = __builtin_amdgcn_mfma_f32_16x16x32_bf16(ah[cur][rt], bl[cur][ct], acc[rt][ct], 0, 0, 0); \
      acc[rt][ct] = __builtin_amdgcn_mfma_f32_16x16x32_bf16(al[cur][rt], bh[cur][ct], acc[rt][ct], 0, 0, 0); } \
  } } while (0)

  // ---- stage 1: H = ReLU(X @ W0 + b0), K=64 (padded)
  ZERO_ACC();
  STAGE(2, Xh, Xl, XSTR, F0h, F0l);
  __syncthreads();
#pragma unroll
  for (int ct = 0; ct < 4; ++ct) {
    int col = wave * 64 + ct * 16 + l16;
    float bias = b0[col];
#pragma unroll
    for (int rt = 0; rt < NRT; ++rt)
#pragma unroll
      for (int r = 0; r < 4; ++r) {
        int row = rt * 16 + quad * 4 + r;
        float h = fmaxf(acc[rt][ct][r] + bias, 0.f);
        split2(h, Hh[row * HSTR + col], Hl[row * HSTR + col]);
      }
  }
  __syncthreads();

  // ---- stage 2: E = ReLU(H @ W1 + b1), K=256
  ZERO_ACC();
  STAGE(8, Hh, Hl, HSTR, F1h, F1l);
  __syncthreads();
#pragma unroll
  for (int ct = 0; ct < 4; ++ct) {
    int col = wave * 64 + ct * 16 + l16;
    float bias = b1[col];
#pragma unroll
    for (int rt = 0; rt < NRT; ++rt)
#pragma unroll
      for (int r = 0; r < 4; ++r) {
        int row = rt * 16 + quad * 4 + r;
        float e = fmaxf(acc[rt][ct][r] + bias, 0.f);
        split2(e, Hh[row * HSTR + col], Hl[row * HSTR + col]);
      }
  }
  __syncthreads();

  // ---- stage 3: P = E @ W2 (rp_b folded into Q), K=256, fp32 out
  ZERO_ACC();
  STAGE(8, Hh, Hl, HSTR, F2h, F2l);
#pragma unroll
  for (int ct = 0; ct < 4; ++ct) {
    int col = wave * 64 + ct * 16 + l16;
#pragma unroll
    for (int rt = 0; rt < NRT; ++rt)
#pragma unroll
      for (int r = 0; r < 4; ++r) {
        int row = rt * 16 + quad * 4 + r;
        P[(size_t)(row0 + row) * NF + col] = acc[rt][ct][r];
      }
  }
#undef ZERO_ACC
#undef STAGE
}

// ---------------------------------------------------------------------------
// Fused agg + update (+QR / +pred). 1024 threads = 16 waves/CU.
// P-sweep: thread (c4=(t&63)*4, rr=(t>>6)&3, jq=t>>8) does 16 float4 P loads
// (16B/lane coalescing sweet spot); LDS partial reduce over jq.
// GEMMs: thread (r=t>>8, c=t&255), rows parallel across waves.
// ---------------------------------------------------------------------------
__device__ __forceinline__ void aggupd_head(
    const float* __restrict__ P, const float* __restrict__ obj,
    const float* __restrict__ Q, const float* __restrict__ R,
    const float* __restrict__ ppw, const float* __restrict__ ppb,
    float* A, float* G, float* Gp, int row0, int tid, float& o)
{
  int b = row0 >> 6;
  {
    int c4 = (tid & 63) * 4;
    int rr = (tid >> 6) & 3;
    int jq = tid >> 8;
    float4 q4 = *(const float4*)(Q + (row0 + rr) * NF + c4);
    const float* Pb = P + ((size_t)(row0 + rr) * NN + jq * 16) * NF + c4;
    const float* Rb = R + (size_t)(b * NN + jq * 16) * NF + c4;
    float4 s = make_float4(0.f, 0.f, 0.f, 0.f);
#pragma unroll
    for (int j = 0; j < 16; ++j) {
      float4 p = *(const float4*)(Pb + (size_t)j * NF);
      float4 rv = *(const float4*)(Rb + (size_t)j * NF);
      s.x += fmaxf(p.x + q4.x + rv.x, 0.f);
      s.y += fmaxf(p.y + q4.y + rv.y, 0.f);
      s.z += fmaxf(p.z + q4.z + rv.z, 0.f);
      s.w += fmaxf(p.w + q4.w + rv.w, 0.f);
    }
    *(float4*)(Gp + (jq * 4 + rr) * NF + c4) = s;
  }
  int r = tid >> 8, c = tid & 255;
  A[r * NF + c] = obj[(row0 + r) * NF + c];
  __syncthreads();
  G[r * NF + c] = Gp[(0 * 4 + r) * NF + c] + Gp[(1 * 4 + r) * NF + c]
                + Gp[(2 * 4 + r) * NF + c] + Gp[(3 * 4 + r) * NF + c];
  __syncthreads();
  float a = ppb[c];
#pragma unroll 8
  for (int k = 0; k < NF; ++k) a += A[r * NF + k] * ppw[k * NF + c];
#pragma unroll 8
  for (int k = 0; k < NF; ++k) a += G[r * NF + k] * ppw[(NF + k) * NF + c];
  o = fmaxf(a, 0.f);
}

__global__ __launch_bounds__(1024) void aggupd_qr_kernel(
    const float* __restrict__ P, const float* __restrict__ obj,
    const float* __restrict__ Q, const float* __restrict__ R,
    const float* __restrict__ ppw, const float* __restrict__ ppb,
    const float* __restrict__ rpw, const float* __restrict__ rpb,
    float* __restrict__ obj_out, float* __restrict__ Qo, float* __restrict__ Ro)
{
  __shared__ float A[4 * NF];
  __shared__ float G[4 * NF];
  __shared__ float Gp[16 * NF];
  int tid = threadIdx.x;
  int row0 = blockIdx.x * 4;
  int r = tid >> 8, c = tid & 255;
  float o;
  aggupd_head(P, obj, Q, R, ppw, ppb, A, G, Gp, row0, tid, o);
  __syncthreads();                 // all reads of old A done
  A[r * NF + c] = o;
  obj_out[(row0 + r) * NF + c] = o;
  __syncthreads();
  float a = rpb[c];
#pragma unroll 8
  for (int k = 0; k < NF; ++k) a += A[r * NF + k] * rpw[(256 + k) * NF + c];
  Qo[(row0 + r) * NF + c] = a;
  a = 0.f;
#pragma unroll 8
  for (int k = 0; k < NF; ++k) a += A[r * NF + k] * rpw[(512 + k) * NF + c];
  Ro[(row0 + r) * NF + c] = a;
}

__global__ __launch_bounds__(1024) void aggupd_pred_kernel(
    const float* __restrict__ P, const float* __restrict__ obj,
    const float* __restrict__ Q, const float* __restrict__ R,
    const float* __restrict__ ppw, const float* __restrict__ ppb,
    const float* __restrict__ w0, const float* __restrict__ b0,
    const float* __restrict__ w1, const float* __restrict__ b1,
    float* __restrict__ out)
{
  __shared__ float A[4 * NF];
  __shared__ float G[4 * NF];
  __shared__ float Gp[16 * NF];
  int tid = threadIdx.x;
  int row0 = blockIdx.x * 4;
  int r = tid >> 8, c = tid & 255;
  float o;
  aggupd_head(P, obj, Q, R, ppw, ppb, A, G, Gp, row0, tid, o);
  __syncthreads();                 // old A reads done
  A[r * NF + c] = o;
  __syncthreads();
  // T = ReLU(obj2 @ w0 + b0) -> G (all G reads finished before barrier above)
  float a = b0[c];
#pragma unroll 8
  for (int k = 0; k < NF; ++k) a += A[r * NF + k] * w0[k * NF + c];
  G[r * NF + c] = fmaxf(a, 0.f);
  __syncthreads();
  if (tid < 4 * GG) {
    int rr = tid >> 5, g = tid & 31;
    a = b1[g];
    const float* Tr = G + rr * NF;
#pragma unroll 8
    for (int k = 0; k < NF; ++k) a += Tr[k] * w1[k * GG + g];
    out[(row0 + rr) * GG + g] = tanhf(a);
  }
}

extern "C" void kernel_launch(void* const* d_in, const int* in_sizes, int n_in,
                              void* d_out, int out_size, void* d_ws, size_t ws_size,
                              hipStream_t stream)
{
  const float* attrs     = (const float*)d_in[0];
  const float* states    = (const float*)d_in[1];
  const float* rel_attrs = (const float*)d_in[2];
  // d_in[3] = pstep (==2, structural)
  const float* enc_w0  = (const float*)d_in[4];
  const float* enc_b0  = (const float*)d_in[5];
  const float* enc_w1  = (const float*)d_in[6];
  const float* enc_b1  = (const float*)d_in[7];
  const float* rel_w0  = (const float*)d_in[8];
  const float* rel_b0  = (const float*)d_in[9];
  const float* rel_w1  = (const float*)d_in[10];
  const float* rel_b1  = (const float*)d_in[11];
  const float* rp_w    = (const float*)d_in[12];
  const float* rp_b    = (const float*)d_in[13];
  const float* pp_w    = (const float*)d_in[14];
  const float* pp_b    = (const float*)d_in[15];
  const float* pred_w0 = (const float*)d_in[16];
  const float* pred_b0 = (const float*)d_in[17];
  const float* pred_w1 = (const float*)d_in[18];
  const float* pred_b1 = (const float*)d_in[19];
  float* out = (float*)d_out;

  char* ws = (char*)d_ws;
  float* P    = (float*)ws;                                  // 64 MB
  float* obj0 = P + (size_t)NROWS_REL * NF;
  float* obj1 = obj0 + NROWS_OBJ * NF;
  float* Q0   = obj1 + NROWS_OBJ * NF;
  float* R0   = Q0 + NROWS_OBJ * NF;
  float* Q1   = R0 + NROWS_OBJ * NF;
  float* R1   = Q1 + NROWS_OBJ * NF;
  ushort_t* F0h = (ushort_t*)(R1 + NROWS_OBJ * NF);
  ushort_t* F0l = F0h + F0_ELEMS;
  ushort_t* F1h = F0l + F0_ELEMS;
  ushort_t* F1l = F1h + F1_ELEMS;
  ushort_t* F2h = F1l + F1_ELEMS;
  ushort_t* F2l = F2h + F1_ELEMS;

  enc_qr_prep_kernel<<<NROWS_OBJ / 4, 1024, 0, stream>>>(
      attrs, states, enc_w0, enc_b0, enc_w1, enc_b1, rp_w, rp_b,
      rel_w0, rel_w1, F0h, F0l, F1h, F1l, F2h, F2l, obj0, Q0, R0);
  rel_chain_mfma<<<NROWS_REL / ROWS, 256, 0, stream>>>(attrs, states, rel_attrs,
                                                       F0h, F0l, rel_b0,
                                                       F1h, F1l, rel_b1,
                                                       F2h, F2l, P);
  // pstep 1: agg + update + Q/R (double-buffered Q/R)
  aggupd_qr_kernel<<<NROWS_OBJ / 4, 1024, 0, stream>>>(P, obj0, Q0, R0,
                                                       pp_w, pp_b, rp_w, rp_b,
                                                       obj1, Q1, R1);
  // pstep 2: agg + update + predictor + tanh
  aggupd_pred_kernel<<<NROWS_OBJ / 4, 1024, 0, stream>>>(P, obj1, Q1, R1,
                                                         pp_w, pp_b,
                                                         pred_w0, pred_b0,
                                                         pred_w1, pred_b1, out);
}